// Round 9
// baseline (770.157 us; speedup 1.0000x reference)
//
#include <hip/hip_runtime.h>
#include <cstdint>
#include <cstddef>

#define DD   512
#define NTOK 32768
#define NE   8
#define BM   128
#define RBLK 1024
#define CMAX (2 * NTOK + NE * BM)  // 66560 max routed+padded rows
#define PMAX (CMAX / BM)           // 520 panels

typedef unsigned int  u32;
typedef unsigned short u16;
typedef unsigned long long u64;
using f16x8 = __attribute__((ext_vector_type(8))) _Float16;
using f32x4 = __attribute__((ext_vector_type(4))) float;

__device__ __forceinline__ u16 f16bits(float f) {
    union { _Float16 h; u16 u; } p;
    p.h = (_Float16)f;
    return p.u;
}
__device__ __forceinline__ float h2f(u16 v) {
    union { _Float16 h; u16 u; } p;
    p.u = v;
    return (float)p.h;
}
__device__ __forceinline__ uint4 pack_f16x8(const float4& a, const float4& b) {
    uint4 r;
    r.x = (u32)f16bits(a.x) | ((u32)f16bits(a.y) << 16);
    r.y = (u32)f16bits(a.z) | ((u32)f16bits(a.w) << 16);
    r.z = (u32)f16bits(b.x) | ((u32)f16bits(b.y) << 16);
    r.w = (u32)f16bits(b.z) | ((u32)f16bits(b.w) << 16);
    return r;
}

// ---------------- routing: block-aggregated counts ----------------
__global__ __launch_bounds__(RBLK) void route_kernel(
    const float* __restrict__ x,
    const float* __restrict__ Wg,
    const float* __restrict__ bg,
    int* __restrict__ counts,
    int* __restrict__ eids,
    float* __restrict__ wts) {
    __shared__ int lcnt[NE];
    int tid = threadIdx.x;
    if (tid < NE) lcnt[tid] = 0;
    __syncthreads();

    int i = blockIdx.x * RBLK + tid;
    bool active = (i < NTOK);
    int e0 = 0, e1 = 0;
    if (active) {
        const float* xr = x + (size_t)i * DD + (DD - 3);
        float x0 = xr[0], x1 = xr[1], x2 = xr[2];
        float g[NE];
#pragma unroll
        for (int e = 0; e < NE; e++)
            g[e] = x0 * Wg[e] + x1 * Wg[NE + e] + x2 * Wg[2 * NE + e] + bg[e];
        float v0 = g[0];
#pragma unroll
        for (int e = 1; e < NE; e++) if (g[e] > v0) { v0 = g[e]; e0 = e; }
        float v1 = -3.0e38f; e1 = -1;
#pragma unroll
        for (int e = 0; e < NE; e++) if (e != e0 && g[e] > v1) { v1 = g[e]; e1 = e; }
        float t = expf(v1 - v0);
        float s = 1.0f / (1.0f + t);
        eids[2 * i] = e0; eids[2 * i + 1] = e1;
        wts[2 * i] = s;  wts[2 * i + 1] = t * s;
    }

    int lane = tid & 63;
#pragma unroll
    for (int k = 0; k < 2; k++) {
        int e = active ? (k ? e1 : e0) : -1;
#pragma unroll
        for (int ex = 0; ex < NE; ex++) {
            u64 m = __ballot(e == ex);
            if (m && lane == 0) atomicAdd(&lcnt[ex], __popcll(m));
        }
    }
    __syncthreads();
    if (tid < NE && lcnt[tid]) atomicAdd(&counts[tid], lcnt[tid]);
}

// ---------------- padded prefix sum (pad to BM) ----------------
__global__ void offsets_kernel(const int* __restrict__ counts,
                               int* __restrict__ off,
                               int* __restrict__ cursor) {
    if (threadIdx.x == 0) {
        int acc = 0;
        for (int e = 0; e < NE; e++) {
            off[e] = acc;
            cursor[e] = acc;
            acc += (counts[e] + (BM - 1)) & ~(BM - 1);
        }
        off[NE] = acc;
    }
}

// ---------------- scatter: block/wave-aggregated ----------------
__global__ __launch_bounds__(RBLK) void scatter_kernel(
    const int* __restrict__ eids,
    int* __restrict__ cursor,
    int* __restrict__ list_token,
    int* __restrict__ posl) {
    __shared__ int lcnt[NE], lbase[NE];
    __shared__ int woff[RBLK / 64][NE];
    int tid = threadIdx.x, lane = tid & 63, wv = tid >> 6;
    int i = blockIdx.x * RBLK + tid;
    bool active = (i < NTOK);
    u64 lmask = (1ull << lane) - 1ull;

#pragma unroll
    for (int k = 0; k < 2; k++) {
        if (tid < NE) lcnt[tid] = 0;
        __syncthreads();
        int e = active ? eids[2 * i + k] : -1;
        u64 mymask = 0;
#pragma unroll
        for (int ex = 0; ex < NE; ex++) {
            u64 m = __ballot(e == ex);
            if (e == ex) mymask = m;
            if (m && lane == 0) woff[wv][ex] = atomicAdd(&lcnt[ex], __popcll(m));
        }
        __syncthreads();
        if (tid < NE) lbase[tid] = lcnt[tid] ? atomicAdd(&cursor[tid], lcnt[tid]) : 0;
        __syncthreads();
        if (active) {
            int p = lbase[e] + woff[wv][e] + __popcll(mymask & lmask);
            list_token[p] = i;
            posl[2 * i + k] = p;
        }
        __syncthreads();
    }
}

// ---------------- weight transpose + fp16 convert ----------------
// Wh[e][l][k][n] (l<3) / Wo[e][k][n]  ->  Wt[(e*4+l)][n][k] fp16
__global__ void convert_w(const float* __restrict__ Wh,
                          const float* __restrict__ Wo,
                          u16* __restrict__ Wt) {
    __shared__ float tile[32][33];
    int z = blockIdx.z;             // e*4 + l
    int e = z >> 2, l = z & 3;
    const float* src = (l < 3) ? (Wh + ((size_t)e * 3 + l) * DD * DD)
                               : (Wo + (size_t)e * DD * DD);
    int bx = blockIdx.x, by = blockIdx.y;
    int tx = threadIdx.x, ty = threadIdx.y; // 32 x 8
#pragma unroll
    for (int j = 0; j < 4; j++)
        tile[ty + j * 8][tx] = src[(size_t)(by * 32 + ty + j * 8) * DD + bx * 32 + tx];
    __syncthreads();
    u16* d = Wt + (size_t)z * DD * DD;
#pragma unroll
    for (int j = 0; j < 4; j++) {
        int n = bx * 32 + ty + j * 8;
        int k = by * 32 + tx;
        d[(size_t)n * DD + k] = f16bits(tile[tx][ty + j * 8]);
    }
}

// ---------------- panel-resident fused 4-layer MLP ----------------
// One block owns 128 rows through all 4 layers. Activations live in LDS
// (128x512 fp16, XOR-swizzled). Weights stream global(L2)->reg, no staging.
// 8 waves, wave-tile 128x64 (wave wv owns cols [64*wv, 64*wv+64)).
__global__ __launch_bounds__(512, 2) void fused_mlp(
    const float* __restrict__ x,
    const int* __restrict__ list_token,
    const u16* __restrict__ Wt,
    const float* __restrict__ bh,
    const float* __restrict__ bo,
    const int* __restrict__ ctrl,
    u16* __restrict__ bY)
{
    __shared__ u16 A[BM * DD];          // 128 KiB
    const int* off = ctrl + 8;
    const int rb = blockIdx.x * BM;
    if (rb >= off[NE]) return;
    int e = 0;
#pragma unroll
    for (int s = 1; s < NE; s++) if (rb >= off[s]) e = s;

    const int tid = threadIdx.x;
    const int lane = tid & 63, wv = tid >> 6;
    const int r15 = lane & 15, lg = lane >> 4;

    // ---- layer 0 input: gather x rows, fp32 -> fp16, swizzled LDS ----
    {
        int row = tid >> 2, q = tid & 3;
        int tok = list_token[rb + row];
        const float* xr = x + (size_t)(tok < 0 ? 0 : tok) * DD;
#pragma unroll
        for (int c8 = 0; c8 < 16; c8++) {
            int u = q * 16 + c8;
            float4 f0 = make_float4(0.f, 0.f, 0.f, 0.f), f1 = f0;
            if (tok >= 0) {
                f0 = *(const float4*)(xr + u * 8);
                f1 = *(const float4*)(xr + u * 8 + 4);
            }
            *(uint4*)&A[row * DD + ((u ^ (row & 7)) << 3)] = pack_f16x8(f0, f1);
        }
    }
    __syncthreads();

    // per-lane column (within this wave's 64-col slice) constants
    int colc[4];
#pragma unroll
    for (int ni = 0; ni < 4; ni++) colc[ni] = wv * 64 + ni * 16 + r15;

    for (int l = 0; l < 4; l++) {
        const u16* W = Wt + (size_t)(e * 4 + l) * DD * DD;
        const float* bias = (l < 3) ? (bh + (size_t)(e * 3 + l) * DD)
                                    : (bo + (size_t)e * DD);
        // per-lane B pointers: W[col][k], k-contig; frag base at k = lg*8
        const u16* bp[4];
#pragma unroll
        for (int ni = 0; ni < 4; ni++)
            bp[ni] = W + (size_t)colc[ni] * DD + lg * 8;

        f32x4 acc[8][4];
#pragma unroll
        for (int mi = 0; mi < 8; mi++)
#pragma unroll
            for (int ni = 0; ni < 4; ni++) acc[mi][ni] = (f32x4){0.f, 0.f, 0.f, 0.f};

        // k-loop: 16 steps of BK=32, B 1-deep prefetch, no barriers
        f16x8 Bn[4];
#pragma unroll
        for (int ni = 0; ni < 4; ni++) Bn[ni] = *(const f16x8*)(bp[ni]);
#pragma unroll
        for (int t = 0; t < 16; t++) {
            f16x8 Bc[4];
#pragma unroll
            for (int ni = 0; ni < 4; ni++) Bc[ni] = Bn[ni];
            if (t < 15) {
#pragma unroll
                for (int ni = 0; ni < 4; ni++)
                    Bn[ni] = *(const f16x8*)(bp[ni] + (t + 1) * 32);
            }
            f16x8 Af[8];
#pragma unroll
            for (int mi = 0; mi < 8; mi++) {
                int row = mi * 16 + r15;
                Af[mi] = *(const f16x8*)&A[row * DD + ((((t << 2) + lg) ^ (row & 7)) << 3)];
            }
#pragma unroll
            for (int ni = 0; ni < 4; ni++)
#pragma unroll
                for (int mi = 0; mi < 8; mi++)
                    acc[mi][ni] = __builtin_amdgcn_mfma_f32_16x16x32_f16(Af[mi], Bc[ni], acc[mi][ni], 0, 0, 0);
        }
        __syncthreads();   // all waves done reading A

        // epilogue: bias (+relu); rewrite A in place (l<3) or store y (l==3)
#pragma unroll
        for (int ni = 0; ni < 4; ni++) {
            int col = colc[ni];
            float bb = bias[col];
#pragma unroll
            for (int mi = 0; mi < 8; mi++) {
#pragma unroll
                for (int rr = 0; rr < 4; rr++) {
                    int row = mi * 16 + lg * 4 + rr;
                    float v = acc[mi][ni][rr] + bb;
                    if (l < 3) {
                        v = fmaxf(v, 0.f);
                        A[row * DD + (((col >> 3) ^ (row & 7)) << 3) + (col & 7)] = f16bits(v);
                    } else {
                        bY[(size_t)(rb + row) * DD + col] = f16bits(v);
                    }
                }
            }
        }
        if (l < 3) __syncthreads();
    }
}

// ---------------- combine: out[n] = w0*y[p0] + w1*y[p1] (y fp16) ----------------
__global__ void combine_kernel(const u16* __restrict__ y,
                               const int* __restrict__ posl,
                               const float* __restrict__ wts,
                               float* __restrict__ out) {
    int idx = blockIdx.x * blockDim.x + threadIdx.x;
    if (idx >= NTOK * (DD / 4)) return;
    int i = idx >> 7;
    int j = idx & 127;
    int p0 = posl[2 * i], p1 = posl[2 * i + 1];
    float w0 = wts[2 * i], w1 = wts[2 * i + 1];
    ushort4 a = ((const ushort4*)(y + (size_t)p0 * DD))[j];
    ushort4 b = ((const ushort4*)(y + (size_t)p1 * DD))[j];
    float4 c;
    c.x = w0 * h2f(a.x) + w1 * h2f(b.x);
    c.y = w0 * h2f(a.y) + w1 * h2f(b.y);
    c.z = w0 * h2f(a.z) + w1 * h2f(b.z);
    c.w = w0 * h2f(a.w) + w1 * h2f(b.w);
    ((float4*)(out + (size_t)i * DD))[j] = c;
}

extern "C" void kernel_launch(void* const* d_in, const int* in_sizes, int n_in,
                              void* d_out, int out_size, void* d_ws, size_t ws_size,
                              hipStream_t stream) {
    const float* x  = (const float*)d_in[0];
    const float* Wg = (const float*)d_in[1];
    const float* bg = (const float*)d_in[2];
    const float* Wh = (const float*)d_in[3];
    const float* bh = (const float*)d_in[4];
    const float* Wo = (const float*)d_in[5];
    const float* bo = (const float*)d_in[6];
    float* out = (float*)d_out;

    char* p = (char*)d_ws;
    int* ctrl   = (int*)p;
    int* counts = ctrl;
    int* off    = ctrl + 8;
    int* cursor = ctrl + 17;
    char* q = p + 4096;
    u16* Wt = (u16*)q;      q += (size_t)NE * 4 * DD * DD * 2;   // 16.78 MB
    int* eids = (int*)q;    q += (size_t)NTOK * 2 * 4;
    int* posl = (int*)q;    q += (size_t)NTOK * 2 * 4;
    float* wts = (float*)q; q += (size_t)NTOK * 2 * 4;
    int* list_token = (int*)q; q += (size_t)CMAX * 4;
    q = (char*)(((uintptr_t)q + 255) & ~(uintptr_t)255);
    u16* bY = (u16*)q;                                           // 68 MB fp16

    hipMemsetAsync(ctrl, 0, 4096, stream);
    hipMemsetAsync(list_token, 0xFF, (size_t)CMAX * 4, stream);

    convert_w<<<dim3(16, 16, 32), dim3(32, 8), 0, stream>>>(Wh, Wo, Wt);
    route_kernel<<<(NTOK + RBLK - 1) / RBLK, RBLK, 0, stream>>>(
        x, Wg, bg, counts, eids, wts);
    offsets_kernel<<<1, 64, 0, stream>>>(counts, off, cursor);
    scatter_kernel<<<(NTOK + RBLK - 1) / RBLK, RBLK, 0, stream>>>(
        eids, cursor, list_token, posl);

    fused_mlp<<<PMAX, 512, 0, stream>>>(x, list_token, Wt, bh, bo, ctrl, bY);

    combine_kernel<<<(NTOK * (DD / 4) + 255) / 256, 256, 0, stream>>>(
        bY, posl, wts, out);
}

// Round 10
// 371.899 us; speedup vs baseline: 2.0709x; 2.0709x over previous
//
#include <hip/hip_runtime.h>
#include <cstdint>
#include <cstddef>

#define DD   512
#define NTOK 32768
#define NE   8
#define BM   256
#define BK   64
#define NKT  8                      // 512 / 64 K-tiles
#define RBLK 1024
#define CMAX (2 * NTOK + NE * BM)   // 67584 max routed+padded rows
#define PMAX (CMAX / BM)            // 264 panels

typedef unsigned int  u32;
typedef unsigned short u16;
typedef unsigned long long u64;
using f16x8 = __attribute__((ext_vector_type(8))) _Float16;
using f32x4 = __attribute__((ext_vector_type(4))) float;

__device__ __forceinline__ u16 f16bits(float f) {
    union { _Float16 h; u16 u; } p;
    p.h = (_Float16)f;
    return p.u;
}
__device__ __forceinline__ float h2f(u16 v) {
    union { _Float16 h; u16 u; } p;
    p.u = v;
    return (float)p.h;
}
__device__ __forceinline__ uint4 pack_f16x8(const float4& a, const float4& b) {
    uint4 r;
    r.x = (u32)f16bits(a.x) | ((u32)f16bits(a.y) << 16);
    r.y = (u32)f16bits(a.z) | ((u32)f16bits(a.w) << 16);
    r.z = (u32)f16bits(b.x) | ((u32)f16bits(b.y) << 16);
    r.w = (u32)f16bits(b.z) | ((u32)f16bits(b.w) << 16);
    return r;
}
__device__ __forceinline__ void gl16(const void* src, const u16* ldsdst) {
    __builtin_amdgcn_global_load_lds(
        (const __attribute__((address_space(1))) u32*)src,
        (__attribute__((address_space(3))) u32*)(void*)ldsdst, 16, 0, 0);
}

// ---------------- routing: block-aggregated counts ----------------
__global__ __launch_bounds__(RBLK) void route_kernel(
    const float* __restrict__ x,
    const float* __restrict__ Wg,
    const float* __restrict__ bg,
    int* __restrict__ counts,
    int* __restrict__ eids,
    float* __restrict__ wts) {
    __shared__ int lcnt[NE];
    int tid = threadIdx.x;
    if (tid < NE) lcnt[tid] = 0;
    __syncthreads();

    int i = blockIdx.x * RBLK + tid;
    bool active = (i < NTOK);
    int e0 = 0, e1 = 0;
    if (active) {
        const float* xr = x + (size_t)i * DD + (DD - 3);
        float x0 = xr[0], x1 = xr[1], x2 = xr[2];
        float g[NE];
#pragma unroll
        for (int e = 0; e < NE; e++)
            g[e] = x0 * Wg[e] + x1 * Wg[NE + e] + x2 * Wg[2 * NE + e] + bg[e];
        float v0 = g[0];
#pragma unroll
        for (int e = 1; e < NE; e++) if (g[e] > v0) { v0 = g[e]; e0 = e; }
        float v1 = -3.0e38f; e1 = -1;
#pragma unroll
        for (int e = 0; e < NE; e++) if (e != e0 && g[e] > v1) { v1 = g[e]; e1 = e; }
        float t = expf(v1 - v0);
        float s = 1.0f / (1.0f + t);
        eids[2 * i] = e0; eids[2 * i + 1] = e1;
        wts[2 * i] = s;  wts[2 * i + 1] = t * s;
    }

    int lane = tid & 63;
#pragma unroll
    for (int k = 0; k < 2; k++) {
        int e = active ? (k ? e1 : e0) : -1;
#pragma unroll
        for (int ex = 0; ex < NE; ex++) {
            u64 m = __ballot(e == ex);
            if (m && lane == 0) atomicAdd(&lcnt[ex], __popcll(m));
        }
    }
    __syncthreads();
    if (tid < NE && lcnt[tid]) atomicAdd(&counts[tid], lcnt[tid]);
}

// ---------------- padded prefix sum (pad to BM=256) ----------------
__global__ void offsets_kernel(const int* __restrict__ counts,
                               int* __restrict__ off,
                               int* __restrict__ cursor) {
    if (threadIdx.x == 0) {
        int acc = 0;
        for (int e = 0; e < NE; e++) {
            off[e] = acc;
            cursor[e] = acc;
            acc += (counts[e] + (BM - 1)) & ~(BM - 1);
        }
        off[NE] = acc;
    }
}

// ---------------- scatter: block/wave-aggregated ----------------
__global__ __launch_bounds__(RBLK) void scatter_kernel(
    const int* __restrict__ eids,
    int* __restrict__ cursor,
    int* __restrict__ list_token,
    int* __restrict__ posl) {
    __shared__ int lcnt[NE], lbase[NE];
    __shared__ int woff[RBLK / 64][NE];
    int tid = threadIdx.x, lane = tid & 63, wv = tid >> 6;
    int i = blockIdx.x * RBLK + tid;
    bool active = (i < NTOK);
    u64 lmask = (1ull << lane) - 1ull;

#pragma unroll
    for (int k = 0; k < 2; k++) {
        if (tid < NE) lcnt[tid] = 0;
        __syncthreads();
        int e = active ? eids[2 * i + k] : -1;
        u64 mymask = 0;
#pragma unroll
        for (int ex = 0; ex < NE; ex++) {
            u64 m = __ballot(e == ex);
            if (e == ex) mymask = m;
            if (m && lane == 0) woff[wv][ex] = atomicAdd(&lcnt[ex], __popcll(m));
        }
        __syncthreads();
        if (tid < NE) lbase[tid] = lcnt[tid] ? atomicAdd(&cursor[tid], lcnt[tid]) : 0;
        __syncthreads();
        if (active) {
            int p = lbase[e] + woff[wv][e] + __popcll(mymask & lmask);
            list_token[p] = i;
            posl[2 * i + k] = p;
        }
        __syncthreads();
    }
}

// ---------------- weight transpose + fp16 convert ----------------
// Wh[e][l][k][n] (l<3) / Wo[e][k][n]  ->  Wt[(e*4+l)][n][k] fp16
__global__ void convert_w(const float* __restrict__ Wh,
                          const float* __restrict__ Wo,
                          u16* __restrict__ Wt) {
    __shared__ float tile[32][33];
    int z = blockIdx.z;             // e*4 + l
    int e = z >> 2, l = z & 3;
    const float* src = (l < 3) ? (Wh + ((size_t)e * 3 + l) * DD * DD)
                               : (Wo + (size_t)e * DD * DD);
    int bx = blockIdx.x, by = blockIdx.y;
    int tx = threadIdx.x, ty = threadIdx.y; // 32 x 8
#pragma unroll
    for (int j = 0; j < 4; j++)
        tile[ty + j * 8][tx] = src[(size_t)(by * 32 + ty + j * 8) * DD + bx * 32 + tx];
    __syncthreads();
    u16* d = Wt + (size_t)z * DD * DD;
#pragma unroll
    for (int j = 0; j < 4; j++) {
        int n = bx * 32 + ty + j * 8;
        int k = by * 32 + tx;
        d[(size_t)n * DD + k] = f16bits(tile[tx][ty + j * 8]);
    }
}

// ---------------- gather x rows -> fp16 xg (linear, padded rows zero) ----------------
__global__ void gather_x(const float* __restrict__ x,
                         const int* __restrict__ list_token,
                         const int* __restrict__ off,
                         u16* __restrict__ xg) {
    int idx = blockIdx.x * 256 + threadIdx.x;
    int row = idx >> 6;                 // 64 threads/row, 8 f16 each
    if (row >= off[NE]) return;
    int c8 = idx & 63;
    int tok = list_token[row];
    uint4 v = make_uint4(0, 0, 0, 0);
    if (tok >= 0) {
        const float4* fp = (const float4*)(x + (size_t)tok * DD + c8 * 8);
        v = pack_f16x8(fp[0], fp[1]);
    }
    *(uint4*)&xg[(size_t)row * DD + c8 * 8] = v;
}

// ---------------- 8-phase 256x256xK512 fp16 MFMA GEMM ----------------
// 512 thr = 8 waves (2M x 4N), wave-tile 128x64. LDS 128KB: 2 bufs x
// {A_kh0, A_kh1, B_kh0, B_kh1} halves of [256][32] f16 (16KB each).
// Swizzle: 16B-unit u' = u ^ ((row>>1)&3), pre-swizzled global source.
// Schedule: per K-tile 4 phases (kh x ni-pair); stage 1 half/phase
// (2 gl16/thread); vmcnt(6) once per K-tile; lgkmcnt(0)+sched_barrier
// after barrier; setprio around the 16-MFMA cluster.
template <bool RELU>
__global__ __launch_bounds__(512, 2) void moe_gemm8(
    const u16* __restrict__ Ain,
    const u16* __restrict__ Wt,
    int layer,
    const float* __restrict__ bptr, int bestride,
    const int* __restrict__ off,
    u16* __restrict__ Cout)
{
    __shared__ u16 lds[65536];   // 128 KiB

    const int rb = (int)(blockIdx.x >> 1) * BM;
    if (rb >= off[NE]) return;
    const int cb = (int)(blockIdx.x & 1) * 256;
    int e = 0;
#pragma unroll
    for (int s = 1; s < NE; s++) if (rb >= off[s]) e = s;
    const u16* Wl = Wt + (size_t)(e * 4 + layer) * DD * DD;

    const int tid = threadIdx.x;
    const int lane = tid & 63, wv = tid >> 6;
    const int wm = wv >> 2, wn = wv & 3;
    const int r15 = lane & 15, lg = lane >> 4;

    // staging mapping: chunk c = j*512 + tid; row = c>>2, unit u = c&3
    int srow[2], sdst[2];
    const u16* aSrc[2]; const u16* bSrc[2];
#pragma unroll
    for (int j = 0; j < 2; j++) {
        int c = j * 512 + tid;
        srow[j] = c >> 2;
        int us = (c & 3) ^ ((srow[j] >> 1) & 3);
        aSrc[j] = Ain + (size_t)(rb + srow[j]) * DD + us * 8;
        bSrc[j] = Wl + (size_t)(cb + srow[j]) * DD + us * 8;
        sdst[j] = j * 4096 + wv * 512;        // u16 idx, + lane*8 by gl16
    }

    // frag read offsets (u16 within a half)
    u32 arow[8], brow[4];
#pragma unroll
    for (int mi = 0; mi < 8; mi++) {
        int r = wm * 128 + mi * 16 + r15;
        arow[mi] = (u32)(r * 32 + ((lg ^ ((r >> 1) & 3)) << 3));
    }
#pragma unroll
    for (int ni = 0; ni < 4; ni++) {
        int r = wn * 64 + ni * 16 + r15;
        brow[ni] = (u32)(r * 32 + ((lg ^ ((r >> 1) & 3)) << 3));
    }

    f32x4 acc[8][4];
#pragma unroll
    for (int i = 0; i < 8; i++)
#pragma unroll
        for (int j = 0; j < 4; j++) acc[i][j] = (f32x4){0.f, 0.f, 0.f, 0.f};

    // half base (u16): buf*32768 + isB*16384 + kh*8192
#define STG(tt, isB, kh)                                                  \
    if ((tt) < NKT) {                                                     \
        _Pragma("unroll")                                                 \
        for (int j = 0; j < 2; j++)                                       \
            gl16(((isB) ? bSrc[j] : aSrc[j]) + (tt) * 64 + (kh) * 32,     \
                 &lds[(((tt) & 1) << 15) + ((isB) << 14) + ((kh) << 13) + sdst[j]]); \
    }

    // prologue: tile0 (4 halves), vmcnt(4); tile1 (3 halves), vmcnt(6)
    STG(0, 0, 0); STG(0, 1, 0); STG(0, 0, 1); STG(0, 1, 1);
    asm volatile("s_waitcnt vmcnt(4)" ::: "memory");
    STG(1, 0, 0); STG(1, 1, 0); STG(1, 0, 1);
    asm volatile("s_waitcnt vmcnt(6)" ::: "memory");
    __builtin_amdgcn_s_barrier();

#define PH_MID()                                                \
    __builtin_amdgcn_s_barrier();                               \
    asm volatile("s_waitcnt lgkmcnt(0)" ::: "memory");          \
    __builtin_amdgcn_sched_barrier(0);                          \
    __builtin_amdgcn_s_setprio(1);

    f16x8 a[8], bf2[2];
#pragma unroll 2
    for (int kt = 0; kt < NKT; kt++) {
        const u32 cu = (u32)((kt & 1) << 15);
        // ---- PH1: kh0, ni 0-1 (loads A kh0) ----
#pragma unroll
        for (int mi = 0; mi < 8; mi++) a[mi] = *(const f16x8*)&lds[cu + arow[mi]];
        bf2[0] = *(const f16x8*)&lds[cu + 16384 + brow[0]];
        bf2[1] = *(const f16x8*)&lds[cu + 16384 + brow[1]];
        STG(kt + 1, 1, 1);
        PH_MID();
#pragma unroll
        for (int mi = 0; mi < 8; mi++) {
            acc[mi][0] = __builtin_amdgcn_mfma_f32_16x16x32_f16(a[mi], bf2[0], acc[mi][0], 0, 0, 0);
            acc[mi][1] = __builtin_amdgcn_mfma_f32_16x16x32_f16(a[mi], bf2[1], acc[mi][1], 0, 0, 0);
        }
        __builtin_amdgcn_s_setprio(0);
        __builtin_amdgcn_s_barrier();
        // ---- PH2: kh0, ni 2-3 (A regs live) ----
        bf2[0] = *(const f16x8*)&lds[cu + 16384 + brow[2]];
        bf2[1] = *(const f16x8*)&lds[cu + 16384 + brow[3]];
        STG(kt + 2, 0, 0);
        PH_MID();
#pragma unroll
        for (int mi = 0; mi < 8; mi++) {
            acc[mi][2] = __builtin_amdgcn_mfma_f32_16x16x32_f16(a[mi], bf2[0], acc[mi][2], 0, 0, 0);
            acc[mi][3] = __builtin_amdgcn_mfma_f32_16x16x32_f16(a[mi], bf2[1], acc[mi][3], 0, 0, 0);
        }
        __builtin_amdgcn_s_setprio(0);
        __builtin_amdgcn_s_barrier();
        // ---- PH3: kh1, ni 0-1 (loads A kh1) ----
#pragma unroll
        for (int mi = 0; mi < 8; mi++) a[mi] = *(const f16x8*)&lds[cu + 8192 + arow[mi]];
        bf2[0] = *(const f16x8*)&lds[cu + 24576 + brow[0]];
        bf2[1] = *(const f16x8*)&lds[cu + 24576 + brow[1]];
        STG(kt + 2, 1, 0);
        PH_MID();
#pragma unroll
        for (int mi = 0; mi < 8; mi++) {
            acc[mi][0] = __builtin_amdgcn_mfma_f32_16x16x32_f16(a[mi], bf2[0], acc[mi][0], 0, 0, 0);
            acc[mi][1] = __builtin_amdgcn_mfma_f32_16x16x32_f16(a[mi], bf2[1], acc[mi][1], 0, 0, 0);
        }
        __builtin_amdgcn_s_setprio(0);
        __builtin_amdgcn_s_barrier();
        // ---- PH4: kh1, ni 2-3; vmcnt(6) once per K-tile ----
        bf2[0] = *(const f16x8*)&lds[cu + 24576 + brow[2]];
        bf2[1] = *(const f16x8*)&lds[cu + 24576 + brow[3]];
        STG(kt + 2, 0, 1);
        PH_MID();
#pragma unroll
        for (int mi = 0; mi < 8; mi++) {
            acc[mi][2] = __builtin_amdgcn_mfma_f32_16x16x32_f16(a[mi], bf2[0], acc[mi][2], 0, 0, 0);
            acc[mi][3] = __builtin_amdgcn_mfma_f32_16x16x32_f16(a[mi], bf2[1], acc[mi][3], 0, 0, 0);
        }
        __builtin_amdgcn_s_setprio(0);
        asm volatile("s_waitcnt vmcnt(6)" ::: "memory");
        __builtin_amdgcn_s_barrier();
    }
#undef STG
#undef PH_MID

    // ---- epilogue: bias (+relu), fp16 store ----
#pragma unroll
    for (int ni = 0; ni < 4; ni++) {
        int col = cb + wn * 64 + ni * 16 + r15;
        float bb = bptr[e * bestride + col];
#pragma unroll
        for (int mi = 0; mi < 8; mi++) {
            int row0 = rb + wm * 128 + mi * 16 + lg * 4;
#pragma unroll
            for (int rr = 0; rr < 4; rr++) {
                float v = acc[mi][ni][rr] + bb;
                if (RELU) v = fmaxf(v, 0.f);
                Cout[(size_t)(row0 + rr) * DD + col] = f16bits(v);
            }
        }
    }
}

// ---------------- combine: out[n] = w0*y[p0] + w1*y[p1] (y fp16) ----------------
__global__ void combine_kernel(const u16* __restrict__ y,
                               const int* __restrict__ posl,
                               const float* __restrict__ wts,
                               float* __restrict__ out) {
    int idx = blockIdx.x * blockDim.x + threadIdx.x;
    if (idx >= NTOK * (DD / 4)) return;
    int i = idx >> 7;
    int j = idx & 127;
    int p0 = posl[2 * i], p1 = posl[2 * i + 1];
    float w0 = wts[2 * i], w1 = wts[2 * i + 1];
    ushort4 a = ((const ushort4*)(y + (size_t)p0 * DD))[j];
    ushort4 b = ((const ushort4*)(y + (size_t)p1 * DD))[j];
    float4 c;
    c.x = w0 * h2f(a.x) + w1 * h2f(b.x);
    c.y = w0 * h2f(a.y) + w1 * h2f(b.y);
    c.z = w0 * h2f(a.z) + w1 * h2f(b.z);
    c.w = w0 * h2f(a.w) + w1 * h2f(b.w);
    ((float4*)(out + (size_t)i * DD))[j] = c;
}

extern "C" void kernel_launch(void* const* d_in, const int* in_sizes, int n_in,
                              void* d_out, int out_size, void* d_ws, size_t ws_size,
                              hipStream_t stream) {
    const float* x  = (const float*)d_in[0];
    const float* Wg = (const float*)d_in[1];
    const float* bg = (const float*)d_in[2];
    const float* Wh = (const float*)d_in[3];
    const float* bh = (const float*)d_in[4];
    const float* Wo = (const float*)d_in[5];
    const float* bo = (const float*)d_in[6];
    float* out = (float*)d_out;

    char* p = (char*)d_ws;
    int* ctrl   = (int*)p;
    int* counts = ctrl;
    int* off    = ctrl + 8;
    int* cursor = ctrl + 17;
    char* q = p + 4096;
    u16* Wt = (u16*)q;      q += (size_t)NE * 4 * DD * DD * 2;   // 16.78 MB
    int* eids = (int*)q;    q += (size_t)NTOK * 2 * 4;
    int* posl = (int*)q;    q += (size_t)NTOK * 2 * 4;
    float* wts = (float*)q; q += (size_t)NTOK * 2 * 4;
    int* list_token = (int*)q; q += (size_t)CMAX * 4;
    q = (char*)(((uintptr_t)q + 255) & ~(uintptr_t)255);
    u16* xg = (u16*)q;  q += (size_t)CMAX * DD * 2;              // 69 MB
    u16* b0 = (u16*)q;  q += (size_t)CMAX * DD * 2;
    u16* b1 = (u16*)q;

    hipMemsetAsync(ctrl, 0, 4096, stream);
    hipMemsetAsync(list_token, 0xFF, (size_t)CMAX * 4, stream);

    convert_w<<<dim3(16, 16, 32), dim3(32, 8), 0, stream>>>(Wh, Wo, Wt);
    route_kernel<<<(NTOK + RBLK - 1) / RBLK, RBLK, 0, stream>>>(
        x, Wg, bg, counts, eids, wts);
    offsets_kernel<<<1, 64, 0, stream>>>(counts, off, cursor);
    scatter_kernel<<<(NTOK + RBLK - 1) / RBLK, RBLK, 0, stream>>>(
        eids, cursor, list_token, posl);
    gather_x<<<CMAX / 4, 256, 0, stream>>>(x, list_token, off, xg);

    const unsigned NB = PMAX * 2;   // 528 blocks; idle blocks early-return
    moe_gemm8<true><<<NB, 512, 0, stream>>>(xg, Wt, 0, bh, 3 * DD, off, b0);
    moe_gemm8<true><<<NB, 512, 0, stream>>>(b0, Wt, 1, bh + DD, 3 * DD, off, b1);
    moe_gemm8<true><<<NB, 512, 0, stream>>>(b1, Wt, 2, bh + 2 * DD, 3 * DD, off, xg);
    moe_gemm8<false><<<NB, 512, 0, stream>>>(xg, Wt, 3, bo, DD, off, b0);

    combine_kernel<<<(NTOK * (DD / 4) + 255) / 256, 256, 0, stream>>>(
        b0, posl, wts, out);
}

// Round 11
// 283.622 us; speedup vs baseline: 2.7154x; 1.3113x over previous
//
#include <hip/hip_runtime.h>
#include <cstdint>
#include <cstddef>

#define DD   512
#define NTOK 32768
#define NE   8
#define BM   128
#define BN   128
#define BK   64
#define NT   (DD / BK)   // 8 k-steps
#define RBLK 1024

typedef unsigned int  u32;
typedef unsigned short u16;
typedef unsigned long long u64;
using f16x8 = __attribute__((ext_vector_type(8))) _Float16;
using f32x4 = __attribute__((ext_vector_type(4))) float;

// LDS (u16 units): single buffer {A, B}, each 128x64 f16 (16KB) -> 32KB
#define OA 0
#define OB 8192

__device__ __forceinline__ u16 f16bits(float f) {
    union { _Float16 h; u16 u; } p;
    p.h = (_Float16)f;
    return p.u;
}
__device__ __forceinline__ uint4 pack_f16x8(const float4& a, const float4& b) {
    uint4 r;
    r.x = (u32)f16bits(a.x) | ((u32)f16bits(a.y) << 16);
    r.y = (u32)f16bits(a.z) | ((u32)f16bits(a.w) << 16);
    r.z = (u32)f16bits(b.x) | ((u32)f16bits(b.y) << 16);
    r.w = (u32)f16bits(b.z) | ((u32)f16bits(b.w) << 16);
    return r;
}

__device__ __forceinline__ void gl16(const void* src, const u16* ldsdst) {
    __builtin_amdgcn_global_load_lds(
        (const __attribute__((address_space(1))) u32*)src,
        (__attribute__((address_space(3))) u32*)(void*)ldsdst, 16, 0, 0);
}

// ---------------- routing: block-aggregated counts ----------------
__global__ __launch_bounds__(RBLK) void route_kernel(
    const float* __restrict__ x,
    const float* __restrict__ Wg,
    const float* __restrict__ bg,
    int t0, int T,
    int* __restrict__ counts,
    int* __restrict__ eids,
    float* __restrict__ wts) {
    __shared__ int lcnt[NE];
    int tid = threadIdx.x;
    if (tid < NE) lcnt[tid] = 0;
    __syncthreads();

    int i = blockIdx.x * RBLK + tid;
    bool active = (i < T);
    int e0 = 0, e1 = 0;
    if (active) {
        int n = t0 + i;
        const float* xr = x + (size_t)n * DD + (DD - 3);
        float x0 = xr[0], x1 = xr[1], x2 = xr[2];
        float g[NE];
#pragma unroll
        for (int e = 0; e < NE; e++)
            g[e] = x0 * Wg[e] + x1 * Wg[NE + e] + x2 * Wg[2 * NE + e] + bg[e];
        float v0 = g[0];
#pragma unroll
        for (int e = 1; e < NE; e++) if (g[e] > v0) { v0 = g[e]; e0 = e; }
        float v1 = -3.0e38f; e1 = -1;
#pragma unroll
        for (int e = 0; e < NE; e++) if (e != e0 && g[e] > v1) { v1 = g[e]; e1 = e; }
        float t = expf(v1 - v0);
        float s = 1.0f / (1.0f + t);
        eids[2 * i] = e0; eids[2 * i + 1] = e1;
        wts[2 * i] = s;  wts[2 * i + 1] = t * s;
    }

    int lane = tid & 63;
#pragma unroll
    for (int k = 0; k < 2; k++) {
        int e = active ? (k ? e1 : e0) : -1;
#pragma unroll
        for (int ex = 0; ex < NE; ex++) {
            u64 m = __ballot(e == ex);
            if (m && lane == 0) atomicAdd(&lcnt[ex], __popcll(m));
        }
    }
    __syncthreads();
    if (tid < NE && lcnt[tid]) atomicAdd(&counts[tid], lcnt[tid]);
}

// ---------------- padded prefix sum (pad to BM) ----------------
__global__ void offsets_kernel(const int* __restrict__ counts,
                               int* __restrict__ off,
                               int* __restrict__ cursor) {
    if (threadIdx.x == 0) {
        int acc = 0;
        for (int e = 0; e < NE; e++) {
            off[e] = acc;
            cursor[e] = acc;
            acc += (counts[e] + (BM - 1)) & ~(BM - 1);
        }
        off[NE] = acc;
    }
}

// ---------------- scatter: block/wave-aggregated ----------------
__global__ __launch_bounds__(RBLK) void scatter_kernel(
    int t0, int T,
    const int* __restrict__ eids,
    int* __restrict__ cursor,
    int* __restrict__ list_token,
    int* __restrict__ posl) {
    __shared__ int lcnt[NE], lbase[NE];
    __shared__ int woff[RBLK / 64][NE];
    int tid = threadIdx.x, lane = tid & 63, wv = tid >> 6;
    int i = blockIdx.x * RBLK + tid;
    bool active = (i < T);
    u64 lmask = (1ull << lane) - 1ull;

#pragma unroll
    for (int k = 0; k < 2; k++) {
        if (tid < NE) lcnt[tid] = 0;
        __syncthreads();
        int e = active ? eids[2 * i + k] : -1;
        u64 mymask = 0;
#pragma unroll
        for (int ex = 0; ex < NE; ex++) {
            u64 m = __ballot(e == ex);
            if (e == ex) mymask = m;
            if (m && lane == 0) woff[wv][ex] = atomicAdd(&lcnt[ex], __popcll(m));
        }
        __syncthreads();
        if (tid < NE) lbase[tid] = lcnt[tid] ? atomicAdd(&cursor[tid], lcnt[tid]) : 0;
        __syncthreads();
        if (active) {
            int p = lbase[e] + woff[wv][e] + __popcll(mymask & lmask);
            list_token[p] = t0 + i;
            posl[2 * i + k] = p;
        }
        __syncthreads();
    }
}

// ---------------- weight transpose + fp16 convert ----------------
// Wh[e][l][k][n] (l<3) / Wo[e][k][n]  ->  Wt[(e*4+l)][n][k] fp16
__global__ void convert_w(const float* __restrict__ Wh,
                          const float* __restrict__ Wo,
                          u16* __restrict__ Wt) {
    __shared__ float tile[32][33];
    int z = blockIdx.z;             // e*4 + l
    int e = z >> 2, l = z & 3;
    const float* src = (l < 3) ? (Wh + ((size_t)e * 3 + l) * DD * DD)
                               : (Wo + (size_t)e * DD * DD);
    int bx = blockIdx.x, by = blockIdx.y;
    int tx = threadIdx.x, ty = threadIdx.y; // 32 x 8
#pragma unroll
    for (int j = 0; j < 4; j++)
        tile[ty + j * 8][tx] = src[(size_t)(by * 32 + ty + j * 8) * DD + bx * 32 + tx];
    __syncthreads();
    u16* d = Wt + (size_t)z * DD * DD;
#pragma unroll
    for (int j = 0; j < 4; j++) {
        int n = bx * 32 + ty + j * 8;
        int k = by * 32 + tx;
        d[(size_t)n * DD + k] = f16bits(tile[tx][ty + j * 8]);
    }
}

// ---------------- fp16 MFMA GEMM: 128x128x64-step, 4 waves, wave-tile 64x64 ----------------
template <bool GATHER, bool RELU, bool OUTF32>
__global__ __launch_bounds__(256, 3) void moe_gemm(
    const float* __restrict__ Xf,
    const u16* __restrict__ Ain,          // fp16 activations (when !GATHER)
    const int* __restrict__ list_token,
    const u16* __restrict__ Wt,
    int layer,
    const float* __restrict__ bptr, int bestride,
    const int* __restrict__ off,
    u16* __restrict__ Ch,                 // fp16 output (when !OUTF32)
    float* __restrict__ Cf)
{
    // XCD-bijective swizzle (grid multiple of 8); cb-minor within XCD chunk
    u32 nb = gridDim.x, qq = nb >> 3, bid = blockIdx.x;
    u32 wg = (bid & 7) * qq + (bid >> 3);
    int rb = (int)(wg >> 2) * BM;
    if (rb >= off[NE]) return;
    int cb = (int)(wg & 3) * BN;
    int e = 0;
#pragma unroll
    for (int s = 1; s < NE; s++) if (rb >= off[s]) e = s;

    __shared__ u16 lds[16384];   // 32 KiB

    const int tid = threadIdx.x;
    const int lane = tid & 63, wv = tid >> 6;

    // staging: per array 1024 chunks (128 rows x 8 units of 16B); 4 chunks/thread
    // chunk c = j*256 + tid; row = c>>3, phys unit = c&7,
    // logical (source) unit us = (c&7) ^ (row&7)
    int rowj[4], usj[4];
#pragma unroll
    for (int j = 0; j < 4; j++) {
        int c = j * 256 + tid;
        rowj[j] = c >> 3;
        usj[j]  = (c & 7) ^ (rowj[j] & 7);
    }

    const size_t wbase = ((size_t)e * 4 + layer) * (size_t)DD * DD;
    const u16* bS[4];
    const u16* aS[4];
    const float* aF[4];
    int tokj[4];
#pragma unroll
    for (int j = 0; j < 4; j++) {
        bS[j] = Wt + wbase + (size_t)(cb + rowj[j]) * DD + usj[j] * 8;
        if (GATHER) {
            tokj[j] = list_token[rb + rowj[j]];
            aF[j] = Xf + (size_t)(tokj[j] < 0 ? 0 : tokj[j]) * DD + usj[j] * 8;
        } else {
            aS[j] = Ain + (size_t)(rb + rowj[j]) * DD + usj[j] * 8;
        }
    }
    // wave-uniform LDS chunk bases (u16 idx): chunk (j*256 + wv*64), lane auto x16B
    const int cb8[4] = { wv * 512, 2048 + wv * 512, 4096 + wv * 512, 6144 + wv * 512 };

    // MFMA read mapping: 2x2 wave grid, wave-tile 64x64; kh in {0,1} covers k 0-31/32-63
    const int r15 = lane & 15, lg = lane >> 4;
    const int wr = (wv >> 1) * 64, wc = (wv & 1) * 64;
    u32 aoffk[2][4], boffk[2][4];
#pragma unroll
    for (int kh = 0; kh < 2; kh++)
#pragma unroll
        for (int i = 0; i < 4; i++) {
            int ar = wr + i * 16 + r15;
            aoffk[kh][i] = (u32)(ar * 64 + (((lg + 4 * kh) ^ (ar & 7)) << 3));
            int br = wc + i * 16 + r15;
            boffk[kh][i] = (u32)(br * 64 + (((lg + 4 * kh) ^ (br & 7)) << 3));
        }

    f32x4 acc[4][4];
#pragma unroll
    for (int i = 0; i < 4; i++)
#pragma unroll
        for (int j = 0; j < 4; j++) acc[i][j] = (f32x4){0.f, 0.f, 0.f, 0.f};

    for (int t = 0; t < NT; t++) {
        const int k0 = t * BK;
        // ---- stage tile t (B via gl16; A via gl16 or gathered fp32->fp16) ----
#pragma unroll
        for (int j = 0; j < 4; j++)
            gl16(bS[j] + k0, &lds[OB + cb8[j]]);
        if (GATHER) {
#pragma unroll
            for (int j = 0; j < 4; j++) {
                const float4* fp = (const float4*)(aF[j] + k0);
                float4 f0 = fp[0], f1 = fp[1];
                if (tokj[j] < 0) { f0 = make_float4(0.f, 0.f, 0.f, 0.f); f1 = f0; }
                *(uint4*)&lds[OA + (j * 256 + tid) * 8] = pack_f16x8(f0, f1);
            }
        } else {
#pragma unroll
            for (int j = 0; j < 4; j++)
                gl16(aS[j] + k0, &lds[OA + cb8[j]]);
        }
        __syncthreads();

        // ---- compute: 16 ds_read_b128 + 32 MFMA per wave ----
#pragma unroll
        for (int kh = 0; kh < 2; kh++) {
            f16x8 a[4];
#pragma unroll
            for (int mi = 0; mi < 4; mi++)
                a[mi] = *(const f16x8*)&lds[OA + aoffk[kh][mi]];
#pragma unroll
            for (int ni = 0; ni < 4; ni++) {
                f16x8 b = *(const f16x8*)&lds[OB + boffk[kh][ni]];
#pragma unroll
                for (int mi = 0; mi < 4; mi++)
                    acc[mi][ni] = __builtin_amdgcn_mfma_f32_16x16x32_f16(a[mi], b, acc[mi][ni], 0, 0, 0);
            }
        }
        __syncthreads();
    }

    // ---- epilogue: bias (+relu); write fp32 or fp16 ----
#pragma unroll
    for (int ni = 0; ni < 4; ni++) {
        int col = cb + wc + ni * 16 + r15;
        float bbias = bptr[e * bestride + col];
#pragma unroll
        for (int mi = 0; mi < 4; mi++) {
            int row0 = rb + wr + mi * 16 + lg * 4;
#pragma unroll
            for (int rr = 0; rr < 4; rr++) {
                float v = acc[mi][ni][rr] + bbias;
                if (RELU) v = fmaxf(v, 0.f);
                size_t idx = (size_t)(row0 + rr) * DD + col;
                if (OUTF32) Cf[idx] = v;
                else        Ch[idx] = f16bits(v);
            }
        }
    }
}

// ---------------- combine ----------------
__global__ void combine_kernel(int t0, int T,
                               const float* __restrict__ y,
                               const int* __restrict__ posl,
                               const float* __restrict__ wts,
                               float* __restrict__ out) {
    int idx = blockIdx.x * blockDim.x + threadIdx.x;
    if (idx >= T * (DD / 4)) return;
    int i = idx >> 7;
    int j = idx & 127;
    int p0 = posl[2 * i], p1 = posl[2 * i + 1];
    float w0 = wts[2 * i], w1 = wts[2 * i + 1];
    float4 a = ((const float4*)(y + (size_t)p0 * DD))[j];
    float4 b = ((const float4*)(y + (size_t)p1 * DD))[j];
    float4 c;
    c.x = w0 * a.x + w1 * b.x;
    c.y = w0 * a.y + w1 * b.y;
    c.z = w0 * a.z + w1 * b.z;
    c.w = w0 * a.w + w1 * b.w;
    ((float4*)(out + (size_t)(t0 + i) * DD))[j] = c;
}

extern "C" void kernel_launch(void* const* d_in, const int* in_sizes, int n_in,
                              void* d_out, int out_size, void* d_ws, size_t ws_size,
                              hipStream_t stream) {
    const float* x  = (const float*)d_in[0];
    const float* Wg = (const float*)d_in[1];
    const float* bg = (const float*)d_in[2];
    const float* Wh = (const float*)d_in[3];
    const float* bh = (const float*)d_in[4];
    const float* Wo = (const float*)d_in[5];
    const float* bo = (const float*)d_in[6];
    float* out = (float*)d_out;

    const size_t WT_ELEMS = (size_t)NE * 4 * DD * DD;   // 8.39M fp16
    int T = NTOK;
    while (T > 64) {
        size_t C = 2 * (size_t)T + NE * BM;
        size_t need = 4096 + WT_ELEMS * 2 + 3 * ((size_t)T * 2 * 4)
                    + C * 4 + 512
                    + C * (size_t)DD * 2      // bufA fp16
                    + C * (size_t)DD * 4;     // regionB: bufB fp16 / yf fp32
        if (need <= ws_size) break;
        T >>= 1;
    }
    int phases = (NTOK + T - 1) / T;
    size_t C = 2 * (size_t)T + NE * BM;

    char* p = (char*)d_ws;
    int* counts = (int*)p;
    int* off    = (int*)(p + 64);
    int* cursor = (int*)(p + 128);
    char* q = p + 4096;
    u16* Wt = (u16*)q;    q += WT_ELEMS * 2;
    int* eids = (int*)q;  q += (size_t)T * 2 * 4;
    int* posl = (int*)q;  q += (size_t)T * 2 * 4;
    float* wts = (float*)q; q += (size_t)T * 2 * 4;
    int* list_token = (int*)q; q += C * 4;
    q = (char*)(((uintptr_t)q + 255) & ~(uintptr_t)255);
    u16* bufA = (u16*)q;  q += C * DD * 2;
    u16* bufB = (u16*)q;                       // aliases yf (fp32) below
    float* yf = (float*)bufB;                  // regionB: C*DD*4 bytes

    convert_w<<<dim3(16, 16, 32), dim3(32, 8), 0, stream>>>(Wh, Wo, Wt);

    for (int ph = 0; ph < phases; ph++) {
        int t0 = ph * T;
        int Tc = (NTOK - t0 < T) ? (NTOK - t0) : T;

        hipMemsetAsync(counts, 0, 256, stream);
        hipMemsetAsync(list_token, 0xFF, C * 4, stream);

        route_kernel<<<(Tc + RBLK - 1) / RBLK, RBLK, 0, stream>>>(
            x, Wg, bg, t0, Tc, counts, eids, wts);
        offsets_kernel<<<1, 64, 0, stream>>>(counts, off, cursor);
        scatter_kernel<<<(Tc + RBLK - 1) / RBLK, RBLK, 0, stream>>>(
            t0, Tc, eids, cursor, list_token, posl);

        // grid: (C/BM) row-panels x 4 col-blocks, 1-D, multiple of 8 for XCD swizzle
        unsigned NB = (unsigned)(C / BM) * (DD / BN);
        moe_gemm<true, true, false><<<NB, 256, 0, stream>>>(
            x, nullptr, list_token, Wt, 0,
            bh, 3 * DD, off, bufA, nullptr);
        moe_gemm<false, true, false><<<NB, 256, 0, stream>>>(
            nullptr, bufA, nullptr, Wt, 1,
            bh + DD, 3 * DD, off, bufB, nullptr);
        moe_gemm<false, true, false><<<NB, 256, 0, stream>>>(
            nullptr, bufB, nullptr, Wt, 2,
            bh + 2 * DD, 3 * DD, off, bufA, nullptr);
        moe_gemm<false, false, true><<<NB, 256, 0, stream>>>(
            nullptr, bufA, nullptr, Wt, 3,
            bo, DD, off, nullptr, yf);

        combine_kernel<<<((size_t)Tc * (DD / 4) + 255) / 256, 256, 0, stream>>>(
            t0, Tc, yf, posl, wts, out);
    }
}

// Round 12
// 261.316 us; speedup vs baseline: 2.9472x; 1.0854x over previous
//
#include <hip/hip_runtime.h>
#include <cstdint>
#include <cstddef>

#define DD   512
#define NTOK 32768
#define NE   8
#define BM   128
#define BN   128
#define BK   64
#define NT   (DD / BK)   // 8 k-steps
#define RBLK 1024

typedef unsigned int  u32;
typedef unsigned short u16;
typedef unsigned long long u64;
using f16x8 = __attribute__((ext_vector_type(8))) _Float16;
using f32x4 = __attribute__((ext_vector_type(4))) float;

// LDS (u16 units): single buffer {A, B}, each 128x64 f16 (16KB) -> 32KB
#define OA 0
#define OB 8192

__device__ __forceinline__ u16 f16bits(float f) {
    union { _Float16 h; u16 u; } p;
    p.h = (_Float16)f;
    return p.u;
}
__device__ __forceinline__ float h2f(u16 v) {
    union { _Float16 h; u16 u; } p;
    p.u = v;
    return (float)p.h;
}
__device__ __forceinline__ uint4 pack_f16x8(const float4& a, const float4& b) {
    uint4 r;
    r.x = (u32)f16bits(a.x) | ((u32)f16bits(a.y) << 16);
    r.y = (u32)f16bits(a.z) | ((u32)f16bits(a.w) << 16);
    r.z = (u32)f16bits(b.x) | ((u32)f16bits(b.y) << 16);
    r.w = (u32)f16bits(b.z) | ((u32)f16bits(b.w) << 16);
    return r;
}

__device__ __forceinline__ void gl16(const void* src, const u16* ldsdst) {
    __builtin_amdgcn_global_load_lds(
        (const __attribute__((address_space(1))) u32*)src,
        (__attribute__((address_space(3))) u32*)(void*)ldsdst, 16, 0, 0);
}

// ---------------- routing: block-aggregated counts ----------------
__global__ __launch_bounds__(RBLK) void route_kernel(
    const float* __restrict__ x,
    const float* __restrict__ Wg,
    const float* __restrict__ bg,
    int t0, int T,
    int* __restrict__ counts,
    int* __restrict__ eids,
    float* __restrict__ wts) {
    __shared__ int lcnt[NE];
    int tid = threadIdx.x;
    if (tid < NE) lcnt[tid] = 0;
    __syncthreads();

    int i = blockIdx.x * RBLK + tid;
    bool active = (i < T);
    int e0 = 0, e1 = 0;
    if (active) {
        int n = t0 + i;
        const float* xr = x + (size_t)n * DD + (DD - 3);
        float x0 = xr[0], x1 = xr[1], x2 = xr[2];
        float g[NE];
#pragma unroll
        for (int e = 0; e < NE; e++)
            g[e] = x0 * Wg[e] + x1 * Wg[NE + e] + x2 * Wg[2 * NE + e] + bg[e];
        float v0 = g[0];
#pragma unroll
        for (int e = 1; e < NE; e++) if (g[e] > v0) { v0 = g[e]; e0 = e; }
        float v1 = -3.0e38f; e1 = -1;
#pragma unroll
        for (int e = 0; e < NE; e++) if (e != e0 && g[e] > v1) { v1 = g[e]; e1 = e; }
        float t = expf(v1 - v0);
        float s = 1.0f / (1.0f + t);
        eids[2 * i] = e0; eids[2 * i + 1] = e1;
        wts[2 * i] = s;  wts[2 * i + 1] = t * s;
    }

    int lane = tid & 63;
#pragma unroll
    for (int k = 0; k < 2; k++) {
        int e = active ? (k ? e1 : e0) : -1;
#pragma unroll
        for (int ex = 0; ex < NE; ex++) {
            u64 m = __ballot(e == ex);
            if (m && lane == 0) atomicAdd(&lcnt[ex], __popcll(m));
        }
    }
    __syncthreads();
    if (tid < NE && lcnt[tid]) atomicAdd(&counts[tid], lcnt[tid]);
}

// ---------------- padded prefix sum (pad to BM) ----------------
__global__ void offsets_kernel(const int* __restrict__ counts,
                               int* __restrict__ off,
                               int* __restrict__ cursor) {
    if (threadIdx.x == 0) {
        int acc = 0;
        for (int e = 0; e < NE; e++) {
            off[e] = acc;
            cursor[e] = acc;
            acc += (counts[e] + (BM - 1)) & ~(BM - 1);
        }
        off[NE] = acc;
    }
}

// ---------------- scatter: block/wave-aggregated ----------------
__global__ __launch_bounds__(RBLK) void scatter_kernel(
    int t0, int T,
    const int* __restrict__ eids,
    int* __restrict__ cursor,
    int* __restrict__ list_token,
    int* __restrict__ posl) {
    __shared__ int lcnt[NE], lbase[NE];
    __shared__ int woff[RBLK / 64][NE];
    int tid = threadIdx.x, lane = tid & 63, wv = tid >> 6;
    int i = blockIdx.x * RBLK + tid;
    bool active = (i < T);
    u64 lmask = (1ull << lane) - 1ull;

#pragma unroll
    for (int k = 0; k < 2; k++) {
        if (tid < NE) lcnt[tid] = 0;
        __syncthreads();
        int e = active ? eids[2 * i + k] : -1;
        u64 mymask = 0;
#pragma unroll
        for (int ex = 0; ex < NE; ex++) {
            u64 m = __ballot(e == ex);
            if (e == ex) mymask = m;
            if (m && lane == 0) woff[wv][ex] = atomicAdd(&lcnt[ex], __popcll(m));
        }
        __syncthreads();
        if (tid < NE) lbase[tid] = lcnt[tid] ? atomicAdd(&cursor[tid], lcnt[tid]) : 0;
        __syncthreads();
        if (active) {
            int p = lbase[e] + woff[wv][e] + __popcll(mymask & lmask);
            list_token[p] = t0 + i;
            posl[2 * i + k] = p;
        }
        __syncthreads();
    }
}

// ---------------- weight transpose + fp16 convert ----------------
// Wh[e][l][k][n] (l<3) / Wo[e][k][n]  ->  Wt[(e*4+l)][n][k] fp16
__global__ void convert_w(const float* __restrict__ Wh,
                          const float* __restrict__ Wo,
                          u16* __restrict__ Wt) {
    __shared__ float tile[32][33];
    int z = blockIdx.z;             // e*4 + l
    int e = z >> 2, l = z & 3;
    const float* src = (l < 3) ? (Wh + ((size_t)e * 3 + l) * DD * DD)
                               : (Wo + (size_t)e * DD * DD);
    int bx = blockIdx.x, by = blockIdx.y;
    int tx = threadIdx.x, ty = threadIdx.y; // 32 x 8
#pragma unroll
    for (int j = 0; j < 4; j++)
        tile[ty + j * 8][tx] = src[(size_t)(by * 32 + ty + j * 8) * DD + bx * 32 + tx];
    __syncthreads();
    u16* d = Wt + (size_t)z * DD * DD;
#pragma unroll
    for (int j = 0; j < 4; j++) {
        int n = bx * 32 + ty + j * 8;
        int k = by * 32 + tx;
        d[(size_t)n * DD + k] = f16bits(tile[tx][ty + j * 8]);
    }
}

// ---------------- fp16 MFMA GEMM: 128x128x64-step, 4 waves, wave-tile 64x64 ----------------
template <bool GATHER, bool RELU>
__global__ __launch_bounds__(256, 3) void moe_gemm(
    const float* __restrict__ Xf,
    const u16* __restrict__ Ain,          // fp16 activations (when !GATHER)
    const int* __restrict__ list_token,
    const u16* __restrict__ Wt,
    int layer,
    const float* __restrict__ bptr, int bestride,
    const int* __restrict__ off,
    u16* __restrict__ Ch)                 // fp16 output
{
    // XCD-bijective swizzle (grid multiple of 8); cb-minor within XCD chunk
    u32 nb = gridDim.x, qq = nb >> 3, bid = blockIdx.x;
    u32 wg = (bid & 7) * qq + (bid >> 3);
    int rb = (int)(wg >> 2) * BM;
    if (rb >= off[NE]) return;
    int cb = (int)(wg & 3) * BN;
    int e = 0;
#pragma unroll
    for (int s = 1; s < NE; s++) if (rb >= off[s]) e = s;

    __shared__ u16 lds[16384];   // 32 KiB

    const int tid = threadIdx.x;
    const int lane = tid & 63, wv = tid >> 6;

    // staging: per array 1024 chunks (128 rows x 8 units of 16B); 4 chunks/thread
    // chunk c = j*256 + tid; row = c>>3, phys unit = c&7,
    // logical (source) unit us = (c&7) ^ (row&7)
    int rowj[4], usj[4];
#pragma unroll
    for (int j = 0; j < 4; j++) {
        int c = j * 256 + tid;
        rowj[j] = c >> 3;
        usj[j]  = (c & 7) ^ (rowj[j] & 7);
    }

    const size_t wbase = ((size_t)e * 4 + layer) * (size_t)DD * DD;
    const u16* bS[4];
    const u16* aS[4];
    const float* aF[4];
    int tokj[4];
#pragma unroll
    for (int j = 0; j < 4; j++) {
        bS[j] = Wt + wbase + (size_t)(cb + rowj[j]) * DD + usj[j] * 8;
        if (GATHER) {
            tokj[j] = list_token[rb + rowj[j]];
            aF[j] = Xf + (size_t)(tokj[j] < 0 ? 0 : tokj[j]) * DD + usj[j] * 8;
        } else {
            aS[j] = Ain + (size_t)(rb + rowj[j]) * DD + usj[j] * 8;
        }
    }
    // wave-uniform LDS chunk bases (u16 idx): chunk (j*256 + wv*64), lane auto x16B
    const int cb8[4] = { wv * 512, 2048 + wv * 512, 4096 + wv * 512, 6144 + wv * 512 };

    // MFMA read mapping: 2x2 wave grid, wave-tile 64x64; kh in {0,1} covers k 0-31/32-63
    const int r15 = lane & 15, lg = lane >> 4;
    const int wr = (wv >> 1) * 64, wc = (wv & 1) * 64;
    u32 aoffk[2][4], boffk[2][4];
#pragma unroll
    for (int kh = 0; kh < 2; kh++)
#pragma unroll
        for (int i = 0; i < 4; i++) {
            int ar = wr + i * 16 + r15;
            aoffk[kh][i] = (u32)(ar * 64 + (((lg + 4 * kh) ^ (ar & 7)) << 3));
            int br = wc + i * 16 + r15;
            boffk[kh][i] = (u32)(br * 64 + (((lg + 4 * kh) ^ (br & 7)) << 3));
        }

    f32x4 acc[4][4];
#pragma unroll
    for (int i = 0; i < 4; i++)
#pragma unroll
        for (int j = 0; j < 4; j++) acc[i][j] = (f32x4){0.f, 0.f, 0.f, 0.f};

    for (int t = 0; t < NT; t++) {
        const int k0 = t * BK;
        // ---- stage tile t (B via gl16; A via gl16 or gathered fp32->fp16) ----
#pragma unroll
        for (int j = 0; j < 4; j++)
            gl16(bS[j] + k0, &lds[OB + cb8[j]]);
        if (GATHER) {
#pragma unroll
            for (int j = 0; j < 4; j++) {
                const float4* fp = (const float4*)(aF[j] + k0);
                float4 f0 = fp[0], f1 = fp[1];
                if (tokj[j] < 0) { f0 = make_float4(0.f, 0.f, 0.f, 0.f); f1 = f0; }
                *(uint4*)&lds[OA + (j * 256 + tid) * 8] = pack_f16x8(f0, f1);
            }
        } else {
#pragma unroll
            for (int j = 0; j < 4; j++)
                gl16(aS[j] + k0, &lds[OA + cb8[j]]);
        }
        __syncthreads();

        // ---- compute: 16 ds_read_b128 + 32 MFMA per wave ----
#pragma unroll
        for (int kh = 0; kh < 2; kh++) {
            f16x8 a[4];
#pragma unroll
            for (int mi = 0; mi < 4; mi++)
                a[mi] = *(const f16x8*)&lds[OA + aoffk[kh][mi]];
#pragma unroll
            for (int ni = 0; ni < 4; ni++) {
                f16x8 b = *(const f16x8*)&lds[OB + boffk[kh][ni]];
#pragma unroll
                for (int mi = 0; mi < 4; mi++)
                    acc[mi][ni] = __builtin_amdgcn_mfma_f32_16x16x32_f16(a[mi], b, acc[mi][ni], 0, 0, 0);
            }
        }
        __syncthreads();
    }

    // ---- epilogue: bias (+relu); fp16 store ----
#pragma unroll
    for (int ni = 0; ni < 4; ni++) {
        int col = cb + wc + ni * 16 + r15;
        float bbias = bptr[e * bestride + col];
#pragma unroll
        for (int mi = 0; mi < 4; mi++) {
            int row0 = rb + wr + mi * 16 + lg * 4;
#pragma unroll
            for (int rr = 0; rr < 4; rr++) {
                float v = acc[mi][ni][rr] + bbias;
                if (RELU) v = fmaxf(v, 0.f);
                Ch[(size_t)(row0 + rr) * DD + col] = f16bits(v);
            }
        }
    }
}

// ---------------- combine: out[n] = w0*y[p0] + w1*y[p1] (y fp16) ----------------
__global__ void combine_kernel(int t0, int T,
                               const u16* __restrict__ y,
                               const int* __restrict__ posl,
                               const float* __restrict__ wts,
                               float* __restrict__ out) {
    int idx = blockIdx.x * blockDim.x + threadIdx.x;
    if (idx >= T * (DD / 4)) return;
    int i = idx >> 7;
    int j = idx & 127;
    int p0 = posl[2 * i], p1 = posl[2 * i + 1];
    float w0 = wts[2 * i], w1 = wts[2 * i + 1];
    ushort4 a = ((const ushort4*)(y + (size_t)p0 * DD))[j];
    ushort4 b = ((const ushort4*)(y + (size_t)p1 * DD))[j];
    float4 c;
    c.x = w0 * h2f(a.x) + w1 * h2f(b.x);
    c.y = w0 * h2f(a.y) + w1 * h2f(b.y);
    c.z = w0 * h2f(a.z) + w1 * h2f(b.z);
    c.w = w0 * h2f(a.w) + w1 * h2f(b.w);
    ((float4*)(out + (size_t)(t0 + i) * DD))[j] = c;
}

extern "C" void kernel_launch(void* const* d_in, const int* in_sizes, int n_in,
                              void* d_out, int out_size, void* d_ws, size_t ws_size,
                              hipStream_t stream) {
    const float* x  = (const float*)d_in[0];
    const float* Wg = (const float*)d_in[1];
    const float* bg = (const float*)d_in[2];
    const float* Wh = (const float*)d_in[3];
    const float* bh = (const float*)d_in[4];
    const float* Wo = (const float*)d_in[5];
    const float* bo = (const float*)d_in[6];
    float* out = (float*)d_out;

    const size_t WT_ELEMS = (size_t)NE * 4 * DD * DD;   // 8.39M fp16
    int T = NTOK;
    while (T > 64) {
        size_t C = 2 * (size_t)T + NE * BM;
        size_t need = 4096 + WT_ELEMS * 2 + 3 * ((size_t)T * 2 * 4)
                    + C * 4 + 512
                    + 3 * (C * (size_t)DD * 2);   // bufA, bufB, bufY fp16
        if (need <= ws_size) break;
        T >>= 1;
    }
    int phases = (NTOK + T - 1) / T;
    size_t C = 2 * (size_t)T + NE * BM;

    char* p = (char*)d_ws;
    int* counts = (int*)p;
    int* off    = (int*)(p + 64);
    int* cursor = (int*)(p + 128);
    char* q = p + 4096;
    u16* Wt = (u16*)q;    q += WT_ELEMS * 2;
    int* eids = (int*)q;  q += (size_t)T * 2 * 4;
    int* posl = (int*)q;  q += (size_t)T * 2 * 4;
    float* wts = (float*)q; q += (size_t)T * 2 * 4;
    int* list_token = (int*)q; q += C * 4;
    q = (char*)(((uintptr_t)q + 255) & ~(uintptr_t)255);
    u16* bufA = (u16*)q;  q += C * DD * 2;
    u16* bufB = (u16*)q;  q += C * DD * 2;
    u16* bufY = (u16*)q;

    convert_w<<<dim3(16, 16, 32), dim3(32, 8), 0, stream>>>(Wh, Wo, Wt);

    for (int ph = 0; ph < phases; ph++) {
        int t0 = ph * T;
        int Tc = (NTOK - t0 < T) ? (NTOK - t0) : T;

        hipMemsetAsync(counts, 0, 256, stream);
        hipMemsetAsync(list_token, 0xFF, C * 4, stream);

        route_kernel<<<(Tc + RBLK - 1) / RBLK, RBLK, 0, stream>>>(
            x, Wg, bg, t0, Tc, counts, eids, wts);
        offsets_kernel<<<1, 64, 0, stream>>>(counts, off, cursor);
        scatter_kernel<<<(Tc + RBLK - 1) / RBLK, RBLK, 0, stream>>>(
            t0, Tc, eids, cursor, list_token, posl);

        // grid: (C/BM) row-panels x 4 col-blocks, 1-D, multiple of 8 for XCD swizzle
        unsigned NB = (unsigned)(C / BM) * (DD / BN);
        moe_gemm<true, true><<<NB, 256, 0, stream>>>(
            x, nullptr, list_token, Wt, 0,
            bh, 3 * DD, off, bufA);
        moe_gemm<false, true><<<NB, 256, 0, stream>>>(
            nullptr, bufA, nullptr, Wt, 1,
            bh + DD, 3 * DD, off, bufB);
        moe_gemm<false, true><<<NB, 256, 0, stream>>>(
            nullptr, bufB, nullptr, Wt, 2,
            bh + 2 * DD, 3 * DD, off, bufA);
        moe_gemm<false, false><<<NB, 256, 0, stream>>>(
            nullptr, bufA, nullptr, Wt, 3,
            bo, DD, off, bufY);

        combine_kernel<<<((size_t)Tc * (DD / 4) + 255) / 256, 256, 0, stream>>>(
            t0, Tc, bufY, posl, wts, out);
    }
}